// Round 9
// baseline (240.705 us; speedup 1.0000x reference)
//
#include <hip/hip_runtime.h>
#include <math.h>

// ---------------------------------------------------------------------------
// CausalSelfAttention fused pipeline, MI355X gfx950.  Round 19.
// r18 post-mortem: totals r13-r18 are flat at ~221 (r15's 211 was an
// outlier, like r17's 97us QKV). Nothing outside QKV ever moved wall clock.
// Ledger: QKV 66.5 | attn3+proj each 50-66 | convert+gate ~11.
// attn3 arithmetic: 4 waves x (8KB K + 8KB V) LDS reads per block-iter =
// 1.35 GB total = 16 B per (q-row x key) -> LDS-port floor ~26us, set by
// rows-per-wave=16. r19: 32 q-rows/wave (128/block, grid 512, 2 blocks/CU):
// both S^T halves share every K-frag read, both PV halves share every
// V-frag read -> LDS bytes/(row.key) halve to 8; block-iters and barriers
// halve. Causal mask = unconditional global-index compare (self-masking,
// single path). QKV/proj/convert/gate byte-identical to r18.
// Workspace: q 8MB | k 8MB | vt 8MB | xb(=y_tiled) 8MB | wb 8MB | gate.
// ---------------------------------------------------------------------------

#define B_    2
#define T_    2048
#define DIM_  1024
#define H_    16
#define HD_   64
#define NROW  (B_ * T_)
#define EPS_  1.1920929e-07f
#define SCALE_ 0.1f
#define LOG2_10K 13.287712379549449f
#define INV2PI 0.15915494309189535f

typedef unsigned short u16;
typedef unsigned int   u32;
typedef __bf16 bf16x8 __attribute__((ext_vector_type(8)));
typedef __bf16 bf16x2 __attribute__((ext_vector_type(2)));
typedef float  f32x4  __attribute__((ext_vector_type(4)));

__device__ __forceinline__ u16 f2b(float f) {
  u32 u = __float_as_uint(f);
  u += 0x7fffu + ((u >> 16) & 1u);       // RNE
  return (u16)(u >> 16);
}
__device__ __forceinline__ u32 pk2(float a, float b) {
#if __has_builtin(__builtin_amdgcn_cvt_pk_bf16_f32)
  bf16x2 r = __builtin_amdgcn_cvt_pk_bf16_f32(a, b);
  return __builtin_bit_cast(u32, r);
#else
  return (u32)f2b(a) | ((u32)f2b(b) << 16);
#endif
}
__device__ __forceinline__ void fast_sincos_rev(float rev, float* s, float* c) {
  const float r = rev - floorf(rev);
#if __has_builtin(__builtin_amdgcn_sinf) && __has_builtin(__builtin_amdgcn_cosf)
  *s = __builtin_amdgcn_sinf(r);
  *c = __builtin_amdgcn_cosf(r);
#else
  *s = __sinf(r * 6.283185307179586f);
  *c = __cosf(r * 6.283185307179586f);
#endif
}
#define MFMA16(a,b,c) __builtin_amdgcn_mfma_f32_16x16x32_bf16((a),(b),(c),0,0,0)

typedef const __attribute__((address_space(1))) unsigned char gbuf_t;
typedef __attribute__((address_space(3))) unsigned char lbuf_t;
__device__ __forceinline__ void gload_lds16(const u16* g, unsigned char* l) {
  __builtin_amdgcn_global_load_lds((gbuf_t*)g, (lbuf_t*)l, 16, 0, 0);
}

// ---------------------------------------------------------------------------
// Convert: x,Wq,Wk,Wv f32 -> bf16 row-major; Wp -> TILED fragment-major
// (chunk(rb,ks)=16x32 contiguous 1KB lane-major).
// ---------------------------------------------------------------------------
__global__ __launch_bounds__(256) void convert_all(
    const float* __restrict__ x, const float* __restrict__ Wq,
    const float* __restrict__ Wk, const float* __restrict__ Wv,
    const float* __restrict__ Wp,
    u16* __restrict__ xb, u16* __restrict__ wb) {
  const int i = blockIdx.x * 256 + threadIdx.x;   // 0 .. 1966079
  if (i < 1835008) {
    const float* src; u16* dst; int off;
    if (i < 1048576)      { src = x;  dst = xb;           off = i; }
    else if (i < 1310720) { src = Wq; dst = wb;           off = i - 1048576; }
    else if (i < 1572864) { src = Wk; dst = wb + 1048576; off = i - 1310720; }
    else                  { src = Wv; dst = wb + 2097152; off = i - 1572864; }
    const float4 f = ((const float4*)src)[off];
    uint2 o;
    o.x = pk2(f.x, f.y);
    o.y = pk2(f.z, f.w);
    ((uint2*)dst)[off] = o;
  } else {
    const int off = i - 1835008;                  // 0..131071 (Wp chunks)
    const int blk = off >> 6, ln = off & 63;
    const int row = ((blk >> 5) << 4) + (ln & 15);
    const int col = ((blk & 31) << 5) + ((ln >> 4) << 3);
    const float4 f0 = *(const float4*)(Wp + (size_t)row * DIM_ + col);
    const float4 f1 = *(const float4*)(Wp + (size_t)row * DIM_ + col + 4);
    uint4 o;
    o.x = pk2(f0.x, f0.y); o.y = pk2(f0.z, f0.w);
    o.z = pk2(f1.x, f1.y); o.w = pk2(f1.z, f1.w);
    ((uint4*)(wb + 3145728))[off] = o;
  }
}

// ---------------------------------------------------------------------------
// QKV GEMM (r12 structure): 128x128 tile, BK=32, LDS 48KB 3-slot ring,
// global_load_lds staging, counted vmcnt(4), one barrier/step.
// grid (32, 24); mode = by>>3: 0 q(rope) 1 k(rope) 2 v(blend, transposed).
// ---------------------------------------------------------------------------
__global__ __launch_bounds__(256) void gemm_qkv(
    const u16* __restrict__ Ab, const u16* __restrict__ Wb,
    u16* __restrict__ qo, u16* __restrict__ ko, u16* __restrict__ vto,
    const float* __restrict__ v1, const float* __restrict__ lambp) {
  __shared__ __attribute__((aligned(16))) unsigned char sm[49152];
  const int tid  = threadIdx.x;
  const int w    = tid >> 6;
  const int lane = tid & 63;
  const int lo = lane & 15, hi = lane >> 4;
  const int m0 = blockIdx.x << 7;
  const int by = blockIdx.y;
  const int mode = by >> 3;
  const int n0 = (by & 7) << 7;
  const u16* W = Wb + (size_t)mode * (DIM_ * DIM_);
  const int wm = w & 1, wn = w >> 1;

  const u16* agA0 = Ab + (size_t)(m0 + (2 * w + 0) * 16 + lo) * DIM_ + (hi << 3);
  const u16* agA1 = Ab + (size_t)(m0 + (2 * w + 1) * 16 + lo) * DIM_ + (hi << 3);
  const u16* agB0 = W  + (size_t)(n0 + (2 * w + 0) * 16 + lo) * DIM_ + (hi << 3);
  const u16* agB1 = W  + (size_t)(n0 + (2 * w + 1) * 16 + lo) * DIM_ + (hi << 3);

  f32x4 acc[4][4];
#pragma unroll
  for (int i = 0; i < 4; ++i)
#pragma unroll
    for (int j = 0; j < 4; ++j) acc[i][j] = (f32x4){0.f, 0.f, 0.f, 0.f};

  {
    unsigned char* ad0 = sm + (2 * w) * 1024;
    gload_lds16(agA0, ad0);
    gload_lds16(agA1, ad0 + 1024);
    gload_lds16(agB0, ad0 + 8192);
    gload_lds16(agB1, ad0 + 9216);
    agA0 += 32; agA1 += 32; agB0 += 32; agB1 += 32;
    unsigned char* ad1 = sm + 16384 + (2 * w) * 1024;
    gload_lds16(agA0, ad1);
    gload_lds16(agA1, ad1 + 1024);
    gload_lds16(agB0, ad1 + 8192);
    gload_lds16(agB1, ad1 + 9216);
    agA0 += 32; agA1 += 32; agB0 += 32; agB1 += 32;
  }

  int cr = 0, cw = 2;
  for (int kc = 0; kc < DIM_; kc += 32) {
    __builtin_amdgcn_sched_barrier(0);
    if (kc + 32 < DIM_) {
      asm volatile("s_waitcnt vmcnt(4)" ::: "memory");
    } else {
      asm volatile("s_waitcnt vmcnt(0)" ::: "memory");
    }
    __builtin_amdgcn_s_barrier();
    __builtin_amdgcn_sched_barrier(0);
    if (kc + 64 < DIM_) {
      unsigned char* ad = sm + cw * 16384 + (2 * w) * 1024;
      gload_lds16(agA0, ad);
      gload_lds16(agA1, ad + 1024);
      gload_lds16(agB0, ad + 8192);
      gload_lds16(agB1, ad + 9216);
      agA0 += 32; agA1 += 32; agB0 += 32; agB1 += 32;
    }
    const unsigned char* Acur = sm + cr * 16384;
    const unsigned char* Bcur = Acur + 8192;
    bf16x8 bfr[4];
#pragma unroll
    for (int nt = 0; nt < 4; ++nt)
      bfr[nt] = *(const bf16x8*)(Bcur + (((wn * 4 + nt) * 64 + lane) << 4));
#pragma unroll
    for (int mt = 0; mt < 4; ++mt) {
      const bf16x8 af = *(const bf16x8*)(Acur + (((wm * 4 + mt) * 64 + lane) << 4));
#pragma unroll
      for (int nt = 0; nt < 4; ++nt)
        acc[mt][nt] = MFMA16(af, bfr[nt], acc[mt][nt]);
    }
    cr = (cr == 2) ? 0 : cr + 1;
    cw = (cw == 2) ? 0 : cw + 1;
  }

  const int head = (n0 >> 6) + wn;
  if (mode <= 1) {
    u16* C = (mode == 0) ? qo : ko;
    const float if0 = exp2f(-(float)lo * (LOG2_10K / 32.f)) * INV2PI;
    const float if1 = exp2f(-(float)(lo + 16) * (LOG2_10K / 32.f)) * INV2PI;
#pragma unroll
    for (int mt = 0; mt < 4; ++mt)
#pragma unroll
      for (int r = 0; r < 4; ++r) {
        float ss = 0.f;
#pragma unroll
        for (int nt = 0; nt < 4; ++nt) { const float v = acc[mt][nt][r]; ss += v * v; }
        ss += __shfl_xor(ss, 1, 64); ss += __shfl_xor(ss, 2, 64);
        ss += __shfl_xor(ss, 4, 64); ss += __shfl_xor(ss, 8, 64);
        const float scl = rsqrtf(ss * (1.f / 64.f) + EPS_);
        const int row_g = m0 + wm * 64 + mt * 16 + hi * 4 + r;
        const float tpos = (float)(row_g & (T_ - 1));
        float sn0, cs0, sn1, cs1;
        fast_sincos_rev(tpos * if0, &sn0, &cs0);
        fast_sincos_rev(tpos * if1, &sn1, &cs1);
        u16* crow = C + (size_t)row_g * DIM_ + head * HD_;
        const float x10 = acc[mt][0][r] * scl, x11 = acc[mt][1][r] * scl;
        const float x20 = acc[mt][2][r] * scl, x21 = acc[mt][3][r] * scl;
        crow[lo]      = f2b(x10 * cs0 + x20 * sn0);
        crow[16 + lo] = f2b(x11 * cs1 + x21 * sn1);
        crow[32 + lo] = f2b(x20 * cs0 - x10 * sn0);
        crow[48 + lo] = f2b(x21 * cs1 - x11 * sn1);
      }
  } else {
    const float lam = lambp[0];
#pragma unroll
    for (int mt = 0; mt < 4; ++mt)
#pragma unroll
      for (int r = 0; r < 4; ++r) {
        const int row_g = m0 + wm * 64 + mt * 16 + hi * 4 + r;
        const int bb = row_g >> 11, tt = row_g & (T_ - 1);
        const int bh = bb * H_ + head;
        const float* v1r = v1 + (size_t)row_g * DIM_ + head * HD_;
#pragma unroll
        for (int nt = 0; nt < 4; ++nt) {
          const int d = nt * 16 + lo;
          const float ov = (1.f - lam) * acc[mt][nt][r] + lam * v1r[d];
          vto[((size_t)(bh * HD_ + d)) * T_ + tt] = f2b(ov);   // transposed
        }
      }
  }
}

// ---------------------------------------------------------------------------
// Proj GEMM (r15 direct-reg winner): grid 256, full 128x128 tile, A = tiled
// y, B = tiled Wp, no LDS/barriers, E/O ping-pong regs, f32 out.
// ---------------------------------------------------------------------------
__global__ __launch_bounds__(256) void gemm_proj(
    const u16* __restrict__ Ab, const u16* __restrict__ Wb,
    float* __restrict__ fo) {
  const int tid  = threadIdx.x;
  const int w    = tid >> 6;
  const int lane = tid & 63;
  const int lo = lane & 15, hi = lane >> 4;
  const int raw = blockIdx.x;
  const int xcd = raw & 7;
  const int jj  = raw >> 3;
  const int m0 = (xcd * 4 + (jj & 3)) << 7;
  const int n0 = (jj >> 2) << 7;
  const int wm = w & 1, wn = w >> 1;

  const u16* pA = Ab + (size_t)((m0 >> 4) + wm * 4) * 16384 + lane * 8;
  const u16* pB = Wb + (size_t)((n0 >> 4) + wn * 4) * 16384 + lane * 8;

  f32x4 acc[4][4];
#pragma unroll
  for (int i = 0; i < 4; ++i)
#pragma unroll
    for (int j = 0; j < 4; ++j) acc[i][j] = (f32x4){0.f, 0.f, 0.f, 0.f};

  bf16x8 aE[4], bE[4], aO[4], bO[4];
#pragma unroll
  for (int t = 0; t < 4; ++t) {
    aE[t] = *(const bf16x8*)(pA + t * 16384);
    bE[t] = *(const bf16x8*)(pB + t * 16384);
  }
  for (int ks = 0; ks < 32; ks += 2) {
#pragma unroll
    for (int t = 0; t < 4; ++t) {
      aO[t] = *(const bf16x8*)(pA + t * 16384 + (ks + 1) * 512);
      bO[t] = *(const bf16x8*)(pB + t * 16384 + (ks + 1) * 512);
    }
#pragma unroll
    for (int mt = 0; mt < 4; ++mt)
#pragma unroll
      for (int nt = 0; nt < 4; ++nt)
        acc[mt][nt] = MFMA16(aE[mt], bE[nt], acc[mt][nt]);
    const int kn = (ks + 2 < 32) ? (ks + 2) : 0;
#pragma unroll
    for (int t = 0; t < 4; ++t) {
      aE[t] = *(const bf16x8*)(pA + t * 16384 + kn * 512);
      bE[t] = *(const bf16x8*)(pB + t * 16384 + kn * 512);
    }
#pragma unroll
    for (int mt = 0; mt < 4; ++mt)
#pragma unroll
      for (int nt = 0; nt < 4; ++nt)
        acc[mt][nt] = MFMA16(aO[mt], bO[nt], acc[mt][nt]);
  }

#pragma unroll
  for (int mt = 0; mt < 4; ++mt)
#pragma unroll
    for (int r = 0; r < 4; ++r) {
      const int row_g = m0 + wm * 64 + mt * 16 + hi * 4 + r;
      float* orow = fo + (size_t)row_g * DIM_ + n0 + wn * 64;
#pragma unroll
      for (int nt = 0; nt < 4; ++nt) orow[nt * 16 + lo] = acc[mt][nt][r];
    }
}

// ---------------------------------------------------------------------------
// gate[n,h] = sigmoid( sum_{j<12} x[n,j]*Wg[h,j] )
// ---------------------------------------------------------------------------
__global__ __launch_bounds__(256) void gate_kernel(
    const float* __restrict__ x, const float* __restrict__ Wg,
    float* __restrict__ gate) {
  const int id = blockIdx.x * 256 + threadIdx.x;
  const int n = id >> 4, h = id & 15;
  const float* xr = x + (size_t)n * DIM_;
  const float* wr = Wg + h * 12;
  float s = 0.f;
#pragma unroll
  for (int j = 0; j < 12; ++j) s += xr[j] * wr[j];
  gate[id] = 1.f / (1.f + __expf(-s));
}

// ---------------------------------------------------------------------------
// MFMA flash attention, 32 q-rows/wave (128/block). Per iter: 8 K-frag +
// 8 V-frag LDS reads serve BOTH q-halves (32 MFMA) -> LDS bytes per
// (row.key) halved vs r18. Causal mask = unconditional global-index
// compare (self-masking off-diagonal). Ring LDS + gload_lds + counted
// vmcnt + no-max softmax + setprio + tiled-y store.
// grid 512: xcd=raw&7, jj=raw>>3; qtb=15-(jj>>2), bh=xcd*4+(jj&3).
// ---------------------------------------------------------------------------
__global__ __launch_bounds__(256) void attn3(
    const u16* __restrict__ q, const u16* __restrict__ k, const u16* __restrict__ vt,
    const float* __restrict__ gate, u16* __restrict__ yt) {
  __shared__ __attribute__((aligned(16))) unsigned char smem[49152];
  const int tid = threadIdx.x;
  const int wv = tid >> 6, lane = tid & 63, lo = lane & 15, hi = lane >> 4;
  const int raw = blockIdx.x;                  // 0..511
  const int xcd = raw & 7;
  const int jj  = raw >> 3;                    // 0..63
  const int qtb = 15 - (jj >> 2);              // 15..0 (128-row q tiles)
  const int bh = xcd * 4 + (jj & 3);           // 0..31
  const int b = bh >> 4, h = bh & 15;
  const int qb = qtb << 7;
  const int nIterM1 = 2 * qtb + 1;             // key tiles 0..nIterM1 (64 ea)

  const int qrowA = b * T_ + qb + wv * 32 + lo;
  const int qrowB = qrowA + 16;
  const u16* qpA = q + (size_t)qrowA * DIM_ + h * HD_;
  const u16* qpB = q + (size_t)qrowB * DIM_ + h * HD_;
  const bf16x8 qfA0 = *(const bf16x8*)(qpA + hi * 8);
  const bf16x8 qfA1 = *(const bf16x8*)(qpA + 32 + hi * 8);
  const bf16x8 qfB0 = *(const bf16x8*)(qpB + hi * 8);
  const bf16x8 qfB1 = *(const bf16x8*)(qpB + 32 + hi * 8);

  f32x4 oA[4], oB[4];
#pragma unroll
  for (int i = 0; i < 4; ++i) {
    oA[i] = (f32x4){0.f, 0.f, 0.f, 0.f};
    oB[i] = (f32x4){0.f, 0.f, 0.f, 0.f};
  }
  float lrunA = 0.f, lrunB = 0.f;

  // staging addresses (64-key tile granularity), identical map to r18
  const int sl = tid & 63, skh = (tid >> 6) & 1, st0 = tid >> 7;
  const int srow = sl & 15, skk = skh * 32 + ((sl >> 4) << 3);
  const u16* kg0 = k + ((size_t)(b * T_ + st0 * 16 + srow)) * DIM_ + h * HD_ + skk;
  const u16* kg1 = kg0 + (size_t)32 * DIM_;
  const u16* vg0 = vt + ((size_t)(bh * HD_ + st0 * 16 + srow)) * T_ + skk;
  const u16* vg1 = vg0 + (size_t)32 * T_;
  const int wub = (tid >> 6) << 10;

  {  // prologue: stage tiles 0 and 1 (always exist: nIterM1 >= 1)
    gload_lds16(kg0, smem + wub);
    gload_lds16(kg1, smem + 4096 + wub);
    gload_lds16(vg0, smem + 8192 + wub);
    gload_lds16(vg1, smem + 12288 + wub);
    unsigned char* b1 = smem + 16384;
    gload_lds16(kg0 + (size_t)64 * DIM_, b1 + wub);
    gload_lds16(kg1 + (size_t)64 * DIM_, b1 + 4096 + wub);
    gload_lds16(vg0 + 64, b1 + 8192 + wub);
    gload_lds16(vg1 + 64, b1 + 12288 + wub);
  }

  int sr = 0, sw = 2;
  for (int tix = 0; tix <= nIterM1; ++tix) {
    __builtin_amdgcn_sched_barrier(0);
    if (tix < nIterM1) {
      asm volatile("s_waitcnt vmcnt(4)" ::: "memory");
    } else {
      asm volatile("s_waitcnt vmcnt(0)" ::: "memory");
    }
    __builtin_amdgcn_s_barrier();
    __builtin_amdgcn_sched_barrier(0);
    if (tix + 2 <= nIterM1) {
      const size_t ko = (size_t)(tix + 2) * 64 * DIM_;
      const size_t vo = (size_t)(tix + 2) * 64;
      unsigned char* base = smem + sw * 16384;
      gload_lds16(kg0 + ko, base + wub);
      gload_lds16(kg1 + ko, base + 4096 + wub);
      gload_lds16(vg0 + vo, base + 8192 + wub);
      gload_lds16(vg1 + vo, base + 12288 + wub);
    }
    const unsigned char* kb = smem + sr * 16384;
    const unsigned char* vb = kb + 8192;

    f32x4 stlA[4], stlB[4];
#pragma unroll
    for (int kt = 0; kt < 4; ++kt) {
      stlA[kt] = (f32x4){0.f, 0.f, 0.f, 0.f};
      stlB[kt] = (f32x4){0.f, 0.f, 0.f, 0.f};
    }
    __builtin_amdgcn_s_setprio(1);
#pragma unroll
    for (int kh = 0; kh < 2; ++kh) {
      const bf16x8 qA_ = kh ? qfA1 : qfA0;
      const bf16x8 qB_ = kh ? qfB1 : qfB0;
#pragma unroll
      for (int kt = 0; kt < 4; ++kt) {
        const bf16x8 af = *(const bf16x8*)(kb + (((kt * 2 + kh) * 64 + lane) << 4));
        stlA[kt] = MFMA16(af, qA_, stlA[kt]);
        stlB[kt] = MFMA16(af, qB_, stlB[kt]);
      }
    }
    __builtin_amdgcn_s_setprio(0);

    // no-max softmax; mask: key_idx > q_idx, self-masking off-diagonal.
    // key local = kt*16 + hi*4 + r; q local (A) = dq + lo, (B) = dq + 16 + lo
    const int dq = qb + wv * 32 - tix * 64;
    float psA = 0.f, psB = 0.f;
#pragma unroll
    for (int kt = 0; kt < 4; ++kt)
#pragma unroll
      for (int r = 0; r < 4; ++r) {
        const int kl = kt * 16 + hi * 4 + r;
        float sA = stlA[kt][r] * SCALE_;
        float sB = stlB[kt][r] * SCALE_;
        if (kl > dq + lo)      sA = -3e38f;
        if (kl > dq + 16 + lo) sB = -3e38f;
        const float eA = __expf(sA);
        const float eB = __expf(sB);
        stlA[kt][r] = eA; psA += eA;
        stlB[kt][r] = eB; psB += eB;
      }
    psA += __shfl_xor(psA, 16, 64);
    psA += __shfl_xor(psA, 32, 64);
    psB += __shfl_xor(psB, 16, 64);
    psB += __shfl_xor(psB, 32, 64);
    lrunA += psA;
    lrunB += psB;

    u32 pkvA[4][2], pkvB[4][2];
#pragma unroll
    for (int kt = 0; kt < 4; ++kt) {
      pkvA[kt][0] = pk2(stlA[kt][0], stlA[kt][1]);
      pkvA[kt][1] = pk2(stlA[kt][2], stlA[kt][3]);
      pkvB[kt][0] = pk2(stlB[kt][0], stlB[kt][1]);
      pkvB[kt][1] = pk2(stlB[kt][2], stlB[kt][3]);
    }
#pragma unroll
    for (int kh = 0; kh < 2; ++kh) {
      uint4 w4A, w4B;
      u32* wpA = (u32*)&w4A;
      u32* wpB = (u32*)&w4B;
#pragma unroll
      for (int wd = 0; wd < 4; ++wd) {
        const int src = (2 * (hi & 1) + (wd >> 1)) * 16 + lo;
        const u32 aA  = (u32)__shfl((int)pkvA[2 * kh][wd & 1], src, 64);
        const u32 bA  = (u32)__shfl((int)pkvA[2 * kh + 1][wd & 1], src, 64);
        wpA[wd] = (hi < 2) ? aA : bA;
        const u32 aB  = (u32)__shfl((int)pkvB[2 * kh][wd & 1], src, 64);
        const u32 bB  = (u32)__shfl((int)pkvB[2 * kh + 1][wd & 1], src, 64);
        wpB[wd] = (hi < 2) ? aB : bB;
      }
      const bf16x8 pfA = __builtin_bit_cast(bf16x8, w4A);
      const bf16x8 pfB = __builtin_bit_cast(bf16x8, w4B);
      __builtin_amdgcn_s_setprio(1);
#pragma unroll
      for (int dt = 0; dt < 4; ++dt) {
        const bf16x8 vf = *(const bf16x8*)(vb + (((dt * 2 + kh) * 64 + lane) << 4));
        oA[dt] = MFMA16(vf, pfA, oA[dt]);
        oB[dt] = MFMA16(vf, pfB, oB[dt]);
      }
      __builtin_amdgcn_s_setprio(0);
    }
    sr = (sr == 2) ? 0 : sr + 1;
    sw = (sw == 2) ? 0 : sw + 1;
  }

  // epilogue per half: gate/lrun scale + tiled y store
  {
    const float inv = gate[(size_t)qrowA * H_ + h] / lrunA;
    u16* ybase = yt + (size_t)(qrowA >> 4) * 16384 + (size_t)(h * 2) * 512
               + lo * 8 + (hi & 1) * 4;
#pragma unroll
    for (int dt = 0; dt < 4; ++dt) {
      ushort4 pq;
      pq.x = f2b(oA[dt][0] * inv); pq.y = f2b(oA[dt][1] * inv);
      pq.z = f2b(oA[dt][2] * inv); pq.w = f2b(oA[dt][3] * inv);
      const int c = (dt * 2 + (hi >> 1)) & 3;
      *(ushort4*)(ybase + (dt >> 1) * 512 + c * 128) = pq;
    }
  }
  {
    const float inv = gate[(size_t)qrowB * H_ + h] / lrunB;
    u16* ybase = yt + (size_t)(qrowB >> 4) * 16384 + (size_t)(h * 2) * 512
               + lo * 8 + (hi & 1) * 4;
#pragma unroll
    for (int dt = 0; dt < 4; ++dt) {
      ushort4 pq;
      pq.x = f2b(oB[dt][0] * inv); pq.y = f2b(oB[dt][1] * inv);
      pq.z = f2b(oB[dt][2] * inv); pq.w = f2b(oB[dt][3] * inv);
      const int c = (dt * 2 + (hi >> 1)) & 3;
      *(ushort4*)(ybase + (dt >> 1) * 512 + c * 128) = pq;
    }
  }
}

// ---------------------------------------------------------------------------
extern "C" void kernel_launch(void* const* d_in, const int* in_sizes, int n_in,
                              void* d_out, int out_size, void* d_ws, size_t ws_size,
                              hipStream_t stream) {
  const float* x    = (const float*)d_in[0];
  const float* v1   = (const float*)d_in[1];
  const float* Wq   = (const float*)d_in[2];
  const float* Wk   = (const float*)d_in[3];
  const float* Wv   = (const float*)d_in[4];
  const float* Wp   = (const float*)d_in[5];
  const float* Wg   = (const float*)d_in[6];
  const float* lamb = (const float*)d_in[7];

  const size_t NX = (size_t)NROW * DIM_;        // 4M
  const size_t NW = (size_t)DIM_ * DIM_;        // 1M

  u16* q  = (u16*)d_ws;
  u16* k  = q + NX;
  u16* vt = k + NX;                             // [bh][d][t]
  u16* xb = vt + NX;                            // row-major x; later tiled y
  u16* wb = xb + NX;                            // wq|wk|wv row-major, wp tiled
  float* gate = (float*)(wb + 4 * NW);          // total ws: 40.25 MB

  const dim3 bb(256);

  convert_all<<<dim3(7680), bb, 0, stream>>>(x, Wq, Wk, Wv, Wp, xb, wb);
  gemm_qkv<<<dim3(32, 24), bb, 0, stream>>>(xb, wb, q, k, vt, v1, lamb);
  gate_kernel<<<dim3(NROW * H_ / 256), bb, 0, stream>>>(x, Wg, gate);
  attn3<<<dim3(512), bb, 0, stream>>>(q, k, vt, gate, xb);
  gemm_proj<<<dim3(256), bb, 0, stream>>>(xb, wb + 3 * NW, (float*)d_out);
}

// Round 10
// 231.544 us; speedup vs baseline: 1.0396x; 1.0396x over previous
//
#include <hip/hip_runtime.h>
#include <math.h>

// ---------------------------------------------------------------------------
// CausalSelfAttention fused pipeline, MI355X gfx950.  Round 20.
// r19 post-mortem: attn3 surfaced in counters: 67.3us, VALU 34.8, Mfma 10.5,
// Occ 12.4%, bank-conflict 2.2M (~5%, minor). Dispatch math shows a 41%
// TAIL IMBALANCE: qtb=15-(jj>>2) puts all long blocks in dispatch round 1 ->
// per-CU iteration totals range 20..48 (balanced=34); kernel ends on the
// 48-iter CUs while the rest idle (matches Occ 12.4%). r20:
//  (1) zig-zag pairing: qtb = (t<8)? 15-t : t-8  -> every CU's two blocks
//      sum to exactly 36 iterations. Bijective index remap, zero risk.
//  (2) fold log2e into the attn scale: P = exp2(S*0.1*log2e) via v_exp_f32
//      (natively 2^x) -> deletes 32 serial v_mul per iter.
// QKV/proj/convert/gate byte-identical to r19. (r19's 240.7 total was
// environment-inflated: acquire 179s, NaN/low-clock profiler rows.)
// Workspace: q 8MB | k 8MB | vt 8MB | xb(=y_tiled) 8MB | wb 8MB | gate.
// ---------------------------------------------------------------------------

#define B_    2
#define T_    2048
#define DIM_  1024
#define H_    16
#define HD_   64
#define NROW  (B_ * T_)
#define EPS_  1.1920929e-07f
#define SCALE_ 0.1f
#define SCALE2_ 0.14426950408889634f   /* 0.1 * log2(e) */
#define LOG2_10K 13.287712379549449f
#define INV2PI 0.15915494309189535f

typedef unsigned short u16;
typedef unsigned int   u32;
typedef __bf16 bf16x8 __attribute__((ext_vector_type(8)));
typedef __bf16 bf16x2 __attribute__((ext_vector_type(2)));
typedef float  f32x4  __attribute__((ext_vector_type(4)));

__device__ __forceinline__ u16 f2b(float f) {
  u32 u = __float_as_uint(f);
  u += 0x7fffu + ((u >> 16) & 1u);       // RNE
  return (u16)(u >> 16);
}
__device__ __forceinline__ u32 pk2(float a, float b) {
#if __has_builtin(__builtin_amdgcn_cvt_pk_bf16_f32)
  bf16x2 r = __builtin_amdgcn_cvt_pk_bf16_f32(a, b);
  return __builtin_bit_cast(u32, r);
#else
  return (u32)f2b(a) | ((u32)f2b(b) << 16);
#endif
}
__device__ __forceinline__ void fast_sincos_rev(float rev, float* s, float* c) {
  const float r = rev - floorf(rev);
#if __has_builtin(__builtin_amdgcn_sinf) && __has_builtin(__builtin_amdgcn_cosf)
  *s = __builtin_amdgcn_sinf(r);
  *c = __builtin_amdgcn_cosf(r);
#else
  *s = __sinf(r * 6.283185307179586f);
  *c = __cosf(r * 6.283185307179586f);
#endif
}
// fast 2^x (v_exp_f32 IS 2^x on gfx9+)
__device__ __forceinline__ float fexp2(float x) {
#if __has_builtin(__builtin_amdgcn_exp2f)
  return __builtin_amdgcn_exp2f(x);
#else
  return __expf(x * 0.6931471805599453f);
#endif
}
#define MFMA16(a,b,c) __builtin_amdgcn_mfma_f32_16x16x32_bf16((a),(b),(c),0,0,0)

typedef const __attribute__((address_space(1))) unsigned char gbuf_t;
typedef __attribute__((address_space(3))) unsigned char lbuf_t;
__device__ __forceinline__ void gload_lds16(const u16* g, unsigned char* l) {
  __builtin_amdgcn_global_load_lds((gbuf_t*)g, (lbuf_t*)l, 16, 0, 0);
}

// ---------------------------------------------------------------------------
// Convert: x,Wq,Wk,Wv f32 -> bf16 row-major; Wp -> TILED fragment-major
// (chunk(rb,ks)=16x32 contiguous 1KB lane-major).
// ---------------------------------------------------------------------------
__global__ __launch_bounds__(256) void convert_all(
    const float* __restrict__ x, const float* __restrict__ Wq,
    const float* __restrict__ Wk, const float* __restrict__ Wv,
    const float* __restrict__ Wp,
    u16* __restrict__ xb, u16* __restrict__ wb) {
  const int i = blockIdx.x * 256 + threadIdx.x;   // 0 .. 1966079
  if (i < 1835008) {
    const float* src; u16* dst; int off;
    if (i < 1048576)      { src = x;  dst = xb;           off = i; }
    else if (i < 1310720) { src = Wq; dst = wb;           off = i - 1048576; }
    else if (i < 1572864) { src = Wk; dst = wb + 1048576; off = i - 1310720; }
    else                  { src = Wv; dst = wb + 2097152; off = i - 1572864; }
    const float4 f = ((const float4*)src)[off];
    uint2 o;
    o.x = pk2(f.x, f.y);
    o.y = pk2(f.z, f.w);
    ((uint2*)dst)[off] = o;
  } else {
    const int off = i - 1835008;                  // 0..131071 (Wp chunks)
    const int blk = off >> 6, ln = off & 63;
    const int row = ((blk >> 5) << 4) + (ln & 15);
    const int col = ((blk & 31) << 5) + ((ln >> 4) << 3);
    const float4 f0 = *(const float4*)(Wp + (size_t)row * DIM_ + col);
    const float4 f1 = *(const float4*)(Wp + (size_t)row * DIM_ + col + 4);
    uint4 o;
    o.x = pk2(f0.x, f0.y); o.y = pk2(f0.z, f0.w);
    o.z = pk2(f1.x, f1.y); o.w = pk2(f1.z, f1.w);
    ((uint4*)(wb + 3145728))[off] = o;
  }
}

// ---------------------------------------------------------------------------
// QKV GEMM (r12 structure): 128x128 tile, BK=32, LDS 48KB 3-slot ring,
// global_load_lds staging, counted vmcnt(4), one barrier/step.
// grid (32, 24); mode = by>>3: 0 q(rope) 1 k(rope) 2 v(blend, transposed).
// ---------------------------------------------------------------------------
__global__ __launch_bounds__(256) void gemm_qkv(
    const u16* __restrict__ Ab, const u16* __restrict__ Wb,
    u16* __restrict__ qo, u16* __restrict__ ko, u16* __restrict__ vto,
    const float* __restrict__ v1, const float* __restrict__ lambp) {
  __shared__ __attribute__((aligned(16))) unsigned char sm[49152];
  const int tid  = threadIdx.x;
  const int w    = tid >> 6;
  const int lane = tid & 63;
  const int lo = lane & 15, hi = lane >> 4;
  const int m0 = blockIdx.x << 7;
  const int by = blockIdx.y;
  const int mode = by >> 3;
  const int n0 = (by & 7) << 7;
  const u16* W = Wb + (size_t)mode * (DIM_ * DIM_);
  const int wm = w & 1, wn = w >> 1;

  const u16* agA0 = Ab + (size_t)(m0 + (2 * w + 0) * 16 + lo) * DIM_ + (hi << 3);
  const u16* agA1 = Ab + (size_t)(m0 + (2 * w + 1) * 16 + lo) * DIM_ + (hi << 3);
  const u16* agB0 = W  + (size_t)(n0 + (2 * w + 0) * 16 + lo) * DIM_ + (hi << 3);
  const u16* agB1 = W  + (size_t)(n0 + (2 * w + 1) * 16 + lo) * DIM_ + (hi << 3);

  f32x4 acc[4][4];
#pragma unroll
  for (int i = 0; i < 4; ++i)
#pragma unroll
    for (int j = 0; j < 4; ++j) acc[i][j] = (f32x4){0.f, 0.f, 0.f, 0.f};

  {
    unsigned char* ad0 = sm + (2 * w) * 1024;
    gload_lds16(agA0, ad0);
    gload_lds16(agA1, ad0 + 1024);
    gload_lds16(agB0, ad0 + 8192);
    gload_lds16(agB1, ad0 + 9216);
    agA0 += 32; agA1 += 32; agB0 += 32; agB1 += 32;
    unsigned char* ad1 = sm + 16384 + (2 * w) * 1024;
    gload_lds16(agA0, ad1);
    gload_lds16(agA1, ad1 + 1024);
    gload_lds16(agB0, ad1 + 8192);
    gload_lds16(agB1, ad1 + 9216);
    agA0 += 32; agA1 += 32; agB0 += 32; agB1 += 32;
  }

  int cr = 0, cw = 2;
  for (int kc = 0; kc < DIM_; kc += 32) {
    __builtin_amdgcn_sched_barrier(0);
    if (kc + 32 < DIM_) {
      asm volatile("s_waitcnt vmcnt(4)" ::: "memory");
    } else {
      asm volatile("s_waitcnt vmcnt(0)" ::: "memory");
    }
    __builtin_amdgcn_s_barrier();
    __builtin_amdgcn_sched_barrier(0);
    if (kc + 64 < DIM_) {
      unsigned char* ad = sm + cw * 16384 + (2 * w) * 1024;
      gload_lds16(agA0, ad);
      gload_lds16(agA1, ad + 1024);
      gload_lds16(agB0, ad + 8192);
      gload_lds16(agB1, ad + 9216);
      agA0 += 32; agA1 += 32; agB0 += 32; agB1 += 32;
    }
    const unsigned char* Acur = sm + cr * 16384;
    const unsigned char* Bcur = Acur + 8192;
    bf16x8 bfr[4];
#pragma unroll
    for (int nt = 0; nt < 4; ++nt)
      bfr[nt] = *(const bf16x8*)(Bcur + (((wn * 4 + nt) * 64 + lane) << 4));
#pragma unroll
    for (int mt = 0; mt < 4; ++mt) {
      const bf16x8 af = *(const bf16x8*)(Acur + (((wm * 4 + mt) * 64 + lane) << 4));
#pragma unroll
      for (int nt = 0; nt < 4; ++nt)
        acc[mt][nt] = MFMA16(af, bfr[nt], acc[mt][nt]);
    }
    cr = (cr == 2) ? 0 : cr + 1;
    cw = (cw == 2) ? 0 : cw + 1;
  }

  const int head = (n0 >> 6) + wn;
  if (mode <= 1) {
    u16* C = (mode == 0) ? qo : ko;
    const float if0 = exp2f(-(float)lo * (LOG2_10K / 32.f)) * INV2PI;
    const float if1 = exp2f(-(float)(lo + 16) * (LOG2_10K / 32.f)) * INV2PI;
#pragma unroll
    for (int mt = 0; mt < 4; ++mt)
#pragma unroll
      for (int r = 0; r < 4; ++r) {
        float ss = 0.f;
#pragma unroll
        for (int nt = 0; nt < 4; ++nt) { const float v = acc[mt][nt][r]; ss += v * v; }
        ss += __shfl_xor(ss, 1, 64); ss += __shfl_xor(ss, 2, 64);
        ss += __shfl_xor(ss, 4, 64); ss += __shfl_xor(ss, 8, 64);
        const float scl = rsqrtf(ss * (1.f / 64.f) + EPS_);
        const int row_g = m0 + wm * 64 + mt * 16 + hi * 4 + r;
        const float tpos = (float)(row_g & (T_ - 1));
        float sn0, cs0, sn1, cs1;
        fast_sincos_rev(tpos * if0, &sn0, &cs0);
        fast_sincos_rev(tpos * if1, &sn1, &cs1);
        u16* crow = C + (size_t)row_g * DIM_ + head * HD_;
        const float x10 = acc[mt][0][r] * scl, x11 = acc[mt][1][r] * scl;
        const float x20 = acc[mt][2][r] * scl, x21 = acc[mt][3][r] * scl;
        crow[lo]      = f2b(x10 * cs0 + x20 * sn0);
        crow[16 + lo] = f2b(x11 * cs1 + x21 * sn1);
        crow[32 + lo] = f2b(x20 * cs0 - x10 * sn0);
        crow[48 + lo] = f2b(x21 * cs1 - x11 * sn1);
      }
  } else {
    const float lam = lambp[0];
#pragma unroll
    for (int mt = 0; mt < 4; ++mt)
#pragma unroll
      for (int r = 0; r < 4; ++r) {
        const int row_g = m0 + wm * 64 + mt * 16 + hi * 4 + r;
        const int bb = row_g >> 11, tt = row_g & (T_ - 1);
        const int bh = bb * H_ + head;
        const float* v1r = v1 + (size_t)row_g * DIM_ + head * HD_;
#pragma unroll
        for (int nt = 0; nt < 4; ++nt) {
          const int d = nt * 16 + lo;
          const float ov = (1.f - lam) * acc[mt][nt][r] + lam * v1r[d];
          vto[((size_t)(bh * HD_ + d)) * T_ + tt] = f2b(ov);   // transposed
        }
      }
  }
}

// ---------------------------------------------------------------------------
// Proj GEMM (r15 direct-reg winner): grid 256, full 128x128 tile, A = tiled
// y, B = tiled Wp, no LDS/barriers, E/O ping-pong regs, f32 out.
// ---------------------------------------------------------------------------
__global__ __launch_bounds__(256) void gemm_proj(
    const u16* __restrict__ Ab, const u16* __restrict__ Wb,
    float* __restrict__ fo) {
  const int tid  = threadIdx.x;
  const int w    = tid >> 6;
  const int lane = tid & 63;
  const int lo = lane & 15, hi = lane >> 4;
  const int raw = blockIdx.x;
  const int xcd = raw & 7;
  const int jj  = raw >> 3;
  const int m0 = (xcd * 4 + (jj & 3)) << 7;
  const int n0 = (jj >> 2) << 7;
  const int wm = w & 1, wn = w >> 1;

  const u16* pA = Ab + (size_t)((m0 >> 4) + wm * 4) * 16384 + lane * 8;
  const u16* pB = Wb + (size_t)((n0 >> 4) + wn * 4) * 16384 + lane * 8;

  f32x4 acc[4][4];
#pragma unroll
  for (int i = 0; i < 4; ++i)
#pragma unroll
    for (int j = 0; j < 4; ++j) acc[i][j] = (f32x4){0.f, 0.f, 0.f, 0.f};

  bf16x8 aE[4], bE[4], aO[4], bO[4];
#pragma unroll
  for (int t = 0; t < 4; ++t) {
    aE[t] = *(const bf16x8*)(pA + t * 16384);
    bE[t] = *(const bf16x8*)(pB + t * 16384);
  }
  for (int ks = 0; ks < 32; ks += 2) {
#pragma unroll
    for (int t = 0; t < 4; ++t) {
      aO[t] = *(const bf16x8*)(pA + t * 16384 + (ks + 1) * 512);
      bO[t] = *(const bf16x8*)(pB + t * 16384 + (ks + 1) * 512);
    }
#pragma unroll
    for (int mt = 0; mt < 4; ++mt)
#pragma unroll
      for (int nt = 0; nt < 4; ++nt)
        acc[mt][nt] = MFMA16(aE[mt], bE[nt], acc[mt][nt]);
    const int kn = (ks + 2 < 32) ? (ks + 2) : 0;
#pragma unroll
    for (int t = 0; t < 4; ++t) {
      aE[t] = *(const bf16x8*)(pA + t * 16384 + kn * 512);
      bE[t] = *(const bf16x8*)(pB + t * 16384 + kn * 512);
    }
#pragma unroll
    for (int mt = 0; mt < 4; ++mt)
#pragma unroll
      for (int nt = 0; nt < 4; ++nt)
        acc[mt][nt] = MFMA16(aO[mt], bO[nt], acc[mt][nt]);
  }

#pragma unroll
  for (int mt = 0; mt < 4; ++mt)
#pragma unroll
    for (int r = 0; r < 4; ++r) {
      const int row_g = m0 + wm * 64 + mt * 16 + hi * 4 + r;
      float* orow = fo + (size_t)row_g * DIM_ + n0 + wn * 64;
#pragma unroll
      for (int nt = 0; nt < 4; ++nt) orow[nt * 16 + lo] = acc[mt][nt][r];
    }
}

// ---------------------------------------------------------------------------
// gate[n,h] = sigmoid( sum_{j<12} x[n,j]*Wg[h,j] )
// ---------------------------------------------------------------------------
__global__ __launch_bounds__(256) void gate_kernel(
    const float* __restrict__ x, const float* __restrict__ Wg,
    float* __restrict__ gate) {
  const int id = blockIdx.x * 256 + threadIdx.x;
  const int n = id >> 4, h = id & 15;
  const float* xr = x + (size_t)n * DIM_;
  const float* wr = Wg + h * 12;
  float s = 0.f;
#pragma unroll
  for (int j = 0; j < 12; ++j) s += xr[j] * wr[j];
  gate[id] = 1.f / (1.f + __expf(-s));
}

// ---------------------------------------------------------------------------
// MFMA flash attention, 32 q-rows/wave (128/block). r20: zig-zag qtb
// pairing (every CU's 2 blocks total exactly 36 iters) + exp2-folded
// softmax scale. Ring LDS + gload_lds + counted vmcnt + no-max softmax +
// setprio + tiled-y store.
// ---------------------------------------------------------------------------
__global__ __launch_bounds__(256) void attn3(
    const u16* __restrict__ q, const u16* __restrict__ k, const u16* __restrict__ vt,
    const float* __restrict__ gate, u16* __restrict__ yt) {
  __shared__ __attribute__((aligned(16))) unsigned char smem[49152];
  const int tid = threadIdx.x;
  const int wv = tid >> 6, lane = tid & 63, lo = lane & 15, hi = lane >> 4;
  const int raw = blockIdx.x;                  // 0..511
  const int xcd = raw & 7;
  const int jj  = raw >> 3;                    // 0..63
  const int t_  = jj >> 2;                     // 0..15
  // zig-zag: dispatch round 1 (t<8) gets long blocks 15..8, round 2 gets
  // 0..7 -> CU pair (15-t, t) = constant 36 iterations per CU.
  const int qtb = (t_ < 8) ? (15 - t_) : (t_ - 8);
  const int bh = xcd * 4 + (jj & 3);           // 0..31
  const int b = bh >> 4, h = bh & 15;
  const int qb = qtb << 7;
  const int nIterM1 = 2 * qtb + 1;             // key tiles 0..nIterM1 (64 ea)

  const int qrowA = b * T_ + qb + wv * 32 + lo;
  const int qrowB = qrowA + 16;
  const u16* qpA = q + (size_t)qrowA * DIM_ + h * HD_;
  const u16* qpB = q + (size_t)qrowB * DIM_ + h * HD_;
  const bf16x8 qfA0 = *(const bf16x8*)(qpA + hi * 8);
  const bf16x8 qfA1 = *(const bf16x8*)(qpA + 32 + hi * 8);
  const bf16x8 qfB0 = *(const bf16x8*)(qpB + hi * 8);
  const bf16x8 qfB1 = *(const bf16x8*)(qpB + 32 + hi * 8);

  f32x4 oA[4], oB[4];
#pragma unroll
  for (int i = 0; i < 4; ++i) {
    oA[i] = (f32x4){0.f, 0.f, 0.f, 0.f};
    oB[i] = (f32x4){0.f, 0.f, 0.f, 0.f};
  }
  float lrunA = 0.f, lrunB = 0.f;

  const int sl = tid & 63, skh = (tid >> 6) & 1, st0 = tid >> 7;
  const int srow = sl & 15, skk = skh * 32 + ((sl >> 4) << 3);
  const u16* kg0 = k + ((size_t)(b * T_ + st0 * 16 + srow)) * DIM_ + h * HD_ + skk;
  const u16* kg1 = kg0 + (size_t)32 * DIM_;
  const u16* vg0 = vt + ((size_t)(bh * HD_ + st0 * 16 + srow)) * T_ + skk;
  const u16* vg1 = vg0 + (size_t)32 * T_;
  const int wub = (tid >> 6) << 10;

  {  // prologue: stage tiles 0 and 1 (always exist: nIterM1 >= 1)
    gload_lds16(kg0, smem + wub);
    gload_lds16(kg1, smem + 4096 + wub);
    gload_lds16(vg0, smem + 8192 + wub);
    gload_lds16(vg1, smem + 12288 + wub);
    unsigned char* b1 = smem + 16384;
    gload_lds16(kg0 + (size_t)64 * DIM_, b1 + wub);
    gload_lds16(kg1 + (size_t)64 * DIM_, b1 + 4096 + wub);
    gload_lds16(vg0 + 64, b1 + 8192 + wub);
    gload_lds16(vg1 + 64, b1 + 12288 + wub);
  }

  int sr = 0, sw = 2;
  for (int tix = 0; tix <= nIterM1; ++tix) {
    __builtin_amdgcn_sched_barrier(0);
    if (tix < nIterM1) {
      asm volatile("s_waitcnt vmcnt(4)" ::: "memory");
    } else {
      asm volatile("s_waitcnt vmcnt(0)" ::: "memory");
    }
    __builtin_amdgcn_s_barrier();
    __builtin_amdgcn_sched_barrier(0);
    if (tix + 2 <= nIterM1) {
      const size_t ko = (size_t)(tix + 2) * 64 * DIM_;
      const size_t vo = (size_t)(tix + 2) * 64;
      unsigned char* base = smem + sw * 16384;
      gload_lds16(kg0 + ko, base + wub);
      gload_lds16(kg1 + ko, base + 4096 + wub);
      gload_lds16(vg0 + vo, base + 8192 + wub);
      gload_lds16(vg1 + vo, base + 12288 + wub);
    }
    const unsigned char* kb = smem + sr * 16384;
    const unsigned char* vb = kb + 8192;

    f32x4 stlA[4], stlB[4];
#pragma unroll
    for (int kt = 0; kt < 4; ++kt) {
      stlA[kt] = (f32x4){0.f, 0.f, 0.f, 0.f};
      stlB[kt] = (f32x4){0.f, 0.f, 0.f, 0.f};
    }
    __builtin_amdgcn_s_setprio(1);
#pragma unroll
    for (int kh = 0; kh < 2; ++kh) {
      const bf16x8 qA_ = kh ? qfA1 : qfA0;
      const bf16x8 qB_ = kh ? qfB1 : qfB0;
#pragma unroll
      for (int kt = 0; kt < 4; ++kt) {
        const bf16x8 af = *(const bf16x8*)(kb + (((kt * 2 + kh) * 64 + lane) << 4));
        stlA[kt] = MFMA16(af, qA_, stlA[kt]);
        stlB[kt] = MFMA16(af, qB_, stlB[kt]);
      }
    }
    __builtin_amdgcn_s_setprio(0);

    // no-max softmax via 2^x: P = exp2(S * 0.1 * log2e). Mask: key > q.
    const int dq = qb + wv * 32 - tix * 64;
    float psA = 0.f, psB = 0.f;
#pragma unroll
    for (int kt = 0; kt < 4; ++kt)
#pragma unroll
      for (int r = 0; r < 4; ++r) {
        const int kl = kt * 16 + hi * 4 + r;
        float sA = stlA[kt][r] * SCALE2_;
        float sB = stlB[kt][r] * SCALE2_;
        if (kl > dq + lo)      sA = -3e38f;
        if (kl > dq + 16 + lo) sB = -3e38f;
        const float eA = fexp2(sA);
        const float eB = fexp2(sB);
        stlA[kt][r] = eA; psA += eA;
        stlB[kt][r] = eB; psB += eB;
      }
    psA += __shfl_xor(psA, 16, 64);
    psA += __shfl_xor(psA, 32, 64);
    psB += __shfl_xor(psB, 16, 64);
    psB += __shfl_xor(psB, 32, 64);
    lrunA += psA;
    lrunB += psB;

    u32 pkvA[4][2], pkvB[4][2];
#pragma unroll
    for (int kt = 0; kt < 4; ++kt) {
      pkvA[kt][0] = pk2(stlA[kt][0], stlA[kt][1]);
      pkvA[kt][1] = pk2(stlA[kt][2], stlA[kt][3]);
      pkvB[kt][0] = pk2(stlB[kt][0], stlB[kt][1]);
      pkvB[kt][1] = pk2(stlB[kt][2], stlB[kt][3]);
    }
#pragma unroll
    for (int kh = 0; kh < 2; ++kh) {
      uint4 w4A, w4B;
      u32* wpA = (u32*)&w4A;
      u32* wpB = (u32*)&w4B;
#pragma unroll
      for (int wd = 0; wd < 4; ++wd) {
        const int src = (2 * (hi & 1) + (wd >> 1)) * 16 + lo;
        const u32 aA  = (u32)__shfl((int)pkvA[2 * kh][wd & 1], src, 64);
        const u32 bA  = (u32)__shfl((int)pkvA[2 * kh + 1][wd & 1], src, 64);
        wpA[wd] = (hi < 2) ? aA : bA;
        const u32 aB  = (u32)__shfl((int)pkvB[2 * kh][wd & 1], src, 64);
        const u32 bB  = (u32)__shfl((int)pkvB[2 * kh + 1][wd & 1], src, 64);
        wpB[wd] = (hi < 2) ? aB : bB;
      }
      const bf16x8 pfA = __builtin_bit_cast(bf16x8, w4A);
      const bf16x8 pfB = __builtin_bit_cast(bf16x8, w4B);
      __builtin_amdgcn_s_setprio(1);
#pragma unroll
      for (int dt = 0; dt < 4; ++dt) {
        const bf16x8 vf = *(const bf16x8*)(vb + (((dt * 2 + kh) * 64 + lane) << 4));
        oA[dt] = MFMA16(vf, pfA, oA[dt]);
        oB[dt] = MFMA16(vf, pfB, oB[dt]);
      }
      __builtin_amdgcn_s_setprio(0);
    }
    sr = (sr == 2) ? 0 : sr + 1;
    sw = (sw == 2) ? 0 : sw + 1;
  }

  // epilogue per half: gate/lrun scale + tiled y store
  {
    const float inv = gate[(size_t)qrowA * H_ + h] / lrunA;
    u16* ybase = yt + (size_t)(qrowA >> 4) * 16384 + (size_t)(h * 2) * 512
               + lo * 8 + (hi & 1) * 4;
#pragma unroll
    for (int dt = 0; dt < 4; ++dt) {
      ushort4 pq;
      pq.x = f2b(oA[dt][0] * inv); pq.y = f2b(oA[dt][1] * inv);
      pq.z = f2b(oA[dt][2] * inv); pq.w = f2b(oA[dt][3] * inv);
      const int c = (dt * 2 + (hi >> 1)) & 3;
      *(ushort4*)(ybase + (dt >> 1) * 512 + c * 128) = pq;
    }
  }
  {
    const float inv = gate[(size_t)qrowB * H_ + h] / lrunB;
    u16* ybase = yt + (size_t)(qrowB >> 4) * 16384 + (size_t)(h * 2) * 512
               + lo * 8 + (hi & 1) * 4;
#pragma unroll
    for (int dt = 0; dt < 4; ++dt) {
      ushort4 pq;
      pq.x = f2b(oB[dt][0] * inv); pq.y = f2b(oB[dt][1] * inv);
      pq.z = f2b(oB[dt][2] * inv); pq.w = f2b(oB[dt][3] * inv);
      const int c = (dt * 2 + (hi >> 1)) & 3;
      *(ushort4*)(ybase + (dt >> 1) * 512 + c * 128) = pq;
    }
  }
}

// ---------------------------------------------------------------------------
extern "C" void kernel_launch(void* const* d_in, const int* in_sizes, int n_in,
                              void* d_out, int out_size, void* d_ws, size_t ws_size,
                              hipStream_t stream) {
  const float* x    = (const float*)d_in[0];
  const float* v1   = (const float*)d_in[1];
  const float* Wq   = (const float*)d_in[2];
  const float* Wk   = (const float*)d_in[3];
  const float* Wv   = (const float*)d_in[4];
  const float* Wp   = (const float*)d_in[5];
  const float* Wg   = (const float*)d_in[6];
  const float* lamb = (const float*)d_in[7];

  const size_t NX = (size_t)NROW * DIM_;        // 4M
  const size_t NW = (size_t)DIM_ * DIM_;        // 1M

  u16* q  = (u16*)d_ws;
  u16* k  = q + NX;
  u16* vt = k + NX;                             // [bh][d][t]
  u16* xb = vt + NX;                            // row-major x; later tiled y
  u16* wb = xb + NX;                            // wq|wk|wv row-major, wp tiled
  float* gate = (float*)(wb + 4 * NW);          // total ws: 40.25 MB

  const dim3 bb(256);

  convert_all<<<dim3(7680), bb, 0, stream>>>(x, Wq, Wk, Wv, Wp, xb, wb);
  gemm_qkv<<<dim3(32, 24), bb, 0, stream>>>(xb, wb, q, k, vt, v1, lamb);
  gate_kernel<<<dim3(NROW * H_ / 256), bb, 0, stream>>>(x, Wg, gate);
  attn3<<<dim3(512), bb, 0, stream>>>(q, k, vt, gate, xb);
  gemm_proj<<<dim3(256), bb, 0, stream>>>(xb, wb + 3 * NW, (float*)d_out);
}

// Round 11
// 218.571 us; speedup vs baseline: 1.1013x; 1.0594x over previous
//
#include <hip/hip_runtime.h>
#include <math.h>

// ---------------------------------------------------------------------------
// CausalSelfAttention fused pipeline, MI355X gfx950.  Round 21.
// r20 post-mortem: 32-row attn confirmed net loss (231.5 vs r18's 220.7).
// Zig-zag nulled because with 2 blocks/CU ALL-RESIDENT the pair runs
// concurrently -> makespan = longer block, pairing irrelevant. r18's
// 16-row/1024-block attn (3/CU, qt-descending = LPT with refill) is the
// best measured attn. r21 = r18 exactly, plus the only riskless deltas:
//  (1) attn softmax via exp2 with folded scale (identical math:
//      exp2(S*0.1*log2e) == e^(0.1S); one fewer VALU op/element).
//  (2) gate_kernel merged into convert_all (both read x; gate consumed two
//      launches later, zero hazard) -> one fewer launch gap + kernel.
// QKV = r12 LDS-ring (proven 7x at 66.5us). proj = direct-reg tiled 256.
// Workspace: q 8MB | k 8MB | vt 8MB | xb(=y_tiled) 8MB | wb 8MB | gate.
// ---------------------------------------------------------------------------

#define B_    2
#define T_    2048
#define DIM_  1024
#define H_    16
#define HD_   64
#define NROW  (B_ * T_)
#define EPS_  1.1920929e-07f
#define SCALE2_ 0.14426950408889634f   /* 0.1 * log2(e) */
#define LOG2_10K 13.287712379549449f
#define INV2PI 0.15915494309189535f

typedef unsigned short u16;
typedef unsigned int   u32;
typedef __bf16 bf16x8 __attribute__((ext_vector_type(8)));
typedef __bf16 bf16x2 __attribute__((ext_vector_type(2)));
typedef float  f32x4  __attribute__((ext_vector_type(4)));

__device__ __forceinline__ u16 f2b(float f) {
  u32 u = __float_as_uint(f);
  u += 0x7fffu + ((u >> 16) & 1u);       // RNE
  return (u16)(u >> 16);
}
__device__ __forceinline__ u32 pk2(float a, float b) {
#if __has_builtin(__builtin_amdgcn_cvt_pk_bf16_f32)
  bf16x2 r = __builtin_amdgcn_cvt_pk_bf16_f32(a, b);
  return __builtin_bit_cast(u32, r);
#else
  return (u32)f2b(a) | ((u32)f2b(b) << 16);
#endif
}
__device__ __forceinline__ void fast_sincos_rev(float rev, float* s, float* c) {
  const float r = rev - floorf(rev);
#if __has_builtin(__builtin_amdgcn_sinf) && __has_builtin(__builtin_amdgcn_cosf)
  *s = __builtin_amdgcn_sinf(r);
  *c = __builtin_amdgcn_cosf(r);
#else
  *s = __sinf(r * 6.283185307179586f);
  *c = __cosf(r * 6.283185307179586f);
#endif
}
// fast 2^x (v_exp_f32 IS 2^x on gfx9+)
__device__ __forceinline__ float fexp2(float x) {
#if __has_builtin(__builtin_amdgcn_exp2f)
  return __builtin_amdgcn_exp2f(x);
#else
  return __expf(x * 0.6931471805599453f);
#endif
}
#define MFMA16(a,b,c) __builtin_amdgcn_mfma_f32_16x16x32_bf16((a),(b),(c),0,0,0)

typedef const __attribute__((address_space(1))) unsigned char gbuf_t;
typedef __attribute__((address_space(3))) unsigned char lbuf_t;
__device__ __forceinline__ void gload_lds16(const u16* g, unsigned char* l) {
  __builtin_amdgcn_global_load_lds((gbuf_t*)g, (lbuf_t*)l, 16, 0, 0);
}

// ---------------------------------------------------------------------------
// Convert + gate: x,Wq,Wk,Wv f32 -> bf16 row-major; Wp -> TILED
// fragment-major (chunk(rb,ks)=16x32 contiguous 1KB lane-major);
// tail 65536 threads compute gate[n,h] = sigmoid(x[n,:12] . Wg[h,:]).
// ---------------------------------------------------------------------------
__global__ __launch_bounds__(256) void convert_all(
    const float* __restrict__ x, const float* __restrict__ Wq,
    const float* __restrict__ Wk, const float* __restrict__ Wv,
    const float* __restrict__ Wp, const float* __restrict__ Wg,
    u16* __restrict__ xb, u16* __restrict__ wb, float* __restrict__ gate) {
  const int i = blockIdx.x * 256 + threadIdx.x;   // 0 .. 2031615
  if (i < 1835008) {
    const float* src; u16* dst; int off;
    if (i < 1048576)      { src = x;  dst = xb;           off = i; }
    else if (i < 1310720) { src = Wq; dst = wb;           off = i - 1048576; }
    else if (i < 1572864) { src = Wk; dst = wb + 1048576; off = i - 1310720; }
    else                  { src = Wv; dst = wb + 2097152; off = i - 1572864; }
    const float4 f = ((const float4*)src)[off];
    uint2 o;
    o.x = pk2(f.x, f.y);
    o.y = pk2(f.z, f.w);
    ((uint2*)dst)[off] = o;
  } else if (i < 1966080) {
    const int off = i - 1835008;                  // 0..131071 (Wp chunks)
    const int blk = off >> 6, ln = off & 63;
    const int row = ((blk >> 5) << 4) + (ln & 15);
    const int col = ((blk & 31) << 5) + ((ln >> 4) << 3);
    const float4 f0 = *(const float4*)(Wp + (size_t)row * DIM_ + col);
    const float4 f1 = *(const float4*)(Wp + (size_t)row * DIM_ + col + 4);
    uint4 o;
    o.x = pk2(f0.x, f0.y); o.y = pk2(f0.z, f0.w);
    o.z = pk2(f1.x, f1.y); o.w = pk2(f1.z, f1.w);
    ((uint4*)(wb + 3145728))[off] = o;
  } else {
    const int id = i - 1966080;                   // 0..65535
    const int n = id >> 4, h = id & 15;
    const float* xr = x + (size_t)n * DIM_;
    const float* wr = Wg + h * 12;
    float s = 0.f;
#pragma unroll
    for (int j = 0; j < 12; ++j) s += xr[j] * wr[j];
    gate[id] = 1.f / (1.f + __expf(-s));
  }
}

// ---------------------------------------------------------------------------
// QKV GEMM (r12 structure): 128x128 tile, BK=32, LDS 48KB 3-slot ring,
// global_load_lds staging, counted vmcnt(4), one barrier/step.
// grid (32, 24); mode = by>>3: 0 q(rope) 1 k(rope) 2 v(blend, transposed).
// ---------------------------------------------------------------------------
__global__ __launch_bounds__(256) void gemm_qkv(
    const u16* __restrict__ Ab, const u16* __restrict__ Wb,
    u16* __restrict__ qo, u16* __restrict__ ko, u16* __restrict__ vto,
    const float* __restrict__ v1, const float* __restrict__ lambp) {
  __shared__ __attribute__((aligned(16))) unsigned char sm[49152];
  const int tid  = threadIdx.x;
  const int w    = tid >> 6;
  const int lane = tid & 63;
  const int lo = lane & 15, hi = lane >> 4;
  const int m0 = blockIdx.x << 7;
  const int by = blockIdx.y;
  const int mode = by >> 3;
  const int n0 = (by & 7) << 7;
  const u16* W = Wb + (size_t)mode * (DIM_ * DIM_);
  const int wm = w & 1, wn = w >> 1;

  const u16* agA0 = Ab + (size_t)(m0 + (2 * w + 0) * 16 + lo) * DIM_ + (hi << 3);
  const u16* agA1 = Ab + (size_t)(m0 + (2 * w + 1) * 16 + lo) * DIM_ + (hi << 3);
  const u16* agB0 = W  + (size_t)(n0 + (2 * w + 0) * 16 + lo) * DIM_ + (hi << 3);
  const u16* agB1 = W  + (size_t)(n0 + (2 * w + 1) * 16 + lo) * DIM_ + (hi << 3);

  f32x4 acc[4][4];
#pragma unroll
  for (int i = 0; i < 4; ++i)
#pragma unroll
    for (int j = 0; j < 4; ++j) acc[i][j] = (f32x4){0.f, 0.f, 0.f, 0.f};

  {
    unsigned char* ad0 = sm + (2 * w) * 1024;
    gload_lds16(agA0, ad0);
    gload_lds16(agA1, ad0 + 1024);
    gload_lds16(agB0, ad0 + 8192);
    gload_lds16(agB1, ad0 + 9216);
    agA0 += 32; agA1 += 32; agB0 += 32; agB1 += 32;
    unsigned char* ad1 = sm + 16384 + (2 * w) * 1024;
    gload_lds16(agA0, ad1);
    gload_lds16(agA1, ad1 + 1024);
    gload_lds16(agB0, ad1 + 8192);
    gload_lds16(agB1, ad1 + 9216);
    agA0 += 32; agA1 += 32; agB0 += 32; agB1 += 32;
  }

  int cr = 0, cw = 2;
  for (int kc = 0; kc < DIM_; kc += 32) {
    __builtin_amdgcn_sched_barrier(0);
    if (kc + 32 < DIM_) {
      asm volatile("s_waitcnt vmcnt(4)" ::: "memory");
    } else {
      asm volatile("s_waitcnt vmcnt(0)" ::: "memory");
    }
    __builtin_amdgcn_s_barrier();
    __builtin_amdgcn_sched_barrier(0);
    if (kc + 64 < DIM_) {
      unsigned char* ad = sm + cw * 16384 + (2 * w) * 1024;
      gload_lds16(agA0, ad);
      gload_lds16(agA1, ad + 1024);
      gload_lds16(agB0, ad + 8192);
      gload_lds16(agB1, ad + 9216);
      agA0 += 32; agA1 += 32; agB0 += 32; agB1 += 32;
    }
    const unsigned char* Acur = sm + cr * 16384;
    const unsigned char* Bcur = Acur + 8192;
    bf16x8 bfr[4];
#pragma unroll
    for (int nt = 0; nt < 4; ++nt)
      bfr[nt] = *(const bf16x8*)(Bcur + (((wn * 4 + nt) * 64 + lane) << 4));
#pragma unroll
    for (int mt = 0; mt < 4; ++mt) {
      const bf16x8 af = *(const bf16x8*)(Acur + (((wm * 4 + mt) * 64 + lane) << 4));
#pragma unroll
      for (int nt = 0; nt < 4; ++nt)
        acc[mt][nt] = MFMA16(af, bfr[nt], acc[mt][nt]);
    }
    cr = (cr == 2) ? 0 : cr + 1;
    cw = (cw == 2) ? 0 : cw + 1;
  }

  const int head = (n0 >> 6) + wn;
  if (mode <= 1) {
    u16* C = (mode == 0) ? qo : ko;
    const float if0 = exp2f(-(float)lo * (LOG2_10K / 32.f)) * INV2PI;
    const float if1 = exp2f(-(float)(lo + 16) * (LOG2_10K / 32.f)) * INV2PI;
#pragma unroll
    for (int mt = 0; mt < 4; ++mt)
#pragma unroll
      for (int r = 0; r < 4; ++r) {
        float ss = 0.f;
#pragma unroll
        for (int nt = 0; nt < 4; ++nt) { const float v = acc[mt][nt][r]; ss += v * v; }
        ss += __shfl_xor(ss, 1, 64); ss += __shfl_xor(ss, 2, 64);
        ss += __shfl_xor(ss, 4, 64); ss += __shfl_xor(ss, 8, 64);
        const float scl = rsqrtf(ss * (1.f / 64.f) + EPS_);
        const int row_g = m0 + wm * 64 + mt * 16 + hi * 4 + r;
        const float tpos = (float)(row_g & (T_ - 1));
        float sn0, cs0, sn1, cs1;
        fast_sincos_rev(tpos * if0, &sn0, &cs0);
        fast_sincos_rev(tpos * if1, &sn1, &cs1);
        u16* crow = C + (size_t)row_g * DIM_ + head * HD_;
        const float x10 = acc[mt][0][r] * scl, x11 = acc[mt][1][r] * scl;
        const float x20 = acc[mt][2][r] * scl, x21 = acc[mt][3][r] * scl;
        crow[lo]      = f2b(x10 * cs0 + x20 * sn0);
        crow[16 + lo] = f2b(x11 * cs1 + x21 * sn1);
        crow[32 + lo] = f2b(x20 * cs0 - x10 * sn0);
        crow[48 + lo] = f2b(x21 * cs1 - x11 * sn1);
      }
  } else {
    const float lam = lambp[0];
#pragma unroll
    for (int mt = 0; mt < 4; ++mt)
#pragma unroll
      for (int r = 0; r < 4; ++r) {
        const int row_g = m0 + wm * 64 + mt * 16 + hi * 4 + r;
        const int bb = row_g >> 11, tt = row_g & (T_ - 1);
        const int bh = bb * H_ + head;
        const float* v1r = v1 + (size_t)row_g * DIM_ + head * HD_;
#pragma unroll
        for (int nt = 0; nt < 4; ++nt) {
          const int d = nt * 16 + lo;
          const float ov = (1.f - lam) * acc[mt][nt][r] + lam * v1r[d];
          vto[((size_t)(bh * HD_ + d)) * T_ + tt] = f2b(ov);   // transposed
        }
      }
  }
}

// ---------------------------------------------------------------------------
// Proj GEMM (r15 direct-reg winner): grid 256, full 128x128 tile, A = tiled
// y, B = tiled Wp, no LDS/barriers, E/O ping-pong regs, f32 out.
// ---------------------------------------------------------------------------
__global__ __launch_bounds__(256) void gemm_proj(
    const u16* __restrict__ Ab, const u16* __restrict__ Wb,
    float* __restrict__ fo) {
  const int tid  = threadIdx.x;
  const int w    = tid >> 6;
  const int lane = tid & 63;
  const int lo = lane & 15, hi = lane >> 4;
  const int raw = blockIdx.x;
  const int xcd = raw & 7;
  const int jj  = raw >> 3;
  const int m0 = (xcd * 4 + (jj & 3)) << 7;
  const int n0 = (jj >> 2) << 7;
  const int wm = w & 1, wn = w >> 1;

  const u16* pA = Ab + (size_t)((m0 >> 4) + wm * 4) * 16384 + lane * 8;
  const u16* pB = Wb + (size_t)((n0 >> 4) + wn * 4) * 16384 + lane * 8;

  f32x4 acc[4][4];
#pragma unroll
  for (int i = 0; i < 4; ++i)
#pragma unroll
    for (int j = 0; j < 4; ++j) acc[i][j] = (f32x4){0.f, 0.f, 0.f, 0.f};

  bf16x8 aE[4], bE[4], aO[4], bO[4];
#pragma unroll
  for (int t = 0; t < 4; ++t) {
    aE[t] = *(const bf16x8*)(pA + t * 16384);
    bE[t] = *(const bf16x8*)(pB + t * 16384);
  }
  for (int ks = 0; ks < 32; ks += 2) {
#pragma unroll
    for (int t = 0; t < 4; ++t) {
      aO[t] = *(const bf16x8*)(pA + t * 16384 + (ks + 1) * 512);
      bO[t] = *(const bf16x8*)(pB + t * 16384 + (ks + 1) * 512);
    }
#pragma unroll
    for (int mt = 0; mt < 4; ++mt)
#pragma unroll
      for (int nt = 0; nt < 4; ++nt)
        acc[mt][nt] = MFMA16(aE[mt], bE[nt], acc[mt][nt]);
    const int kn = (ks + 2 < 32) ? (ks + 2) : 0;
#pragma unroll
    for (int t = 0; t < 4; ++t) {
      aE[t] = *(const bf16x8*)(pA + t * 16384 + kn * 512);
      bE[t] = *(const bf16x8*)(pB + t * 16384 + kn * 512);
    }
#pragma unroll
    for (int mt = 0; mt < 4; ++mt)
#pragma unroll
      for (int nt = 0; nt < 4; ++nt)
        acc[mt][nt] = MFMA16(aO[mt], bO[nt], acc[mt][nt]);
  }

#pragma unroll
  for (int mt = 0; mt < 4; ++mt)
#pragma unroll
    for (int r = 0; r < 4; ++r) {
      const int row_g = m0 + wm * 64 + mt * 16 + hi * 4 + r;
      float* orow = fo + (size_t)row_g * DIM_ + n0 + wn * 64;
#pragma unroll
      for (int nt = 0; nt < 4; ++nt) orow[nt * 16 + lo] = acc[mt][nt][r];
    }
}

// ---------------------------------------------------------------------------
// MFMA flash attention — r18 16-row body + exp2-folded softmax.
// Ring LDS + gload_lds + counted vmcnt + no-max softmax + setprio +
// tiled-y store. grid 1024, qt descending (LPT with 3-blocks/CU refill).
// ---------------------------------------------------------------------------
__global__ __launch_bounds__(256) void attn3(
    const u16* __restrict__ q, const u16* __restrict__ k, const u16* __restrict__ vt,
    const float* __restrict__ gate, u16* __restrict__ yt) {
  __shared__ __attribute__((aligned(16))) unsigned char smem[49152];
  const int tid = threadIdx.x;
  const int wv = tid >> 6, lane = tid & 63, lo = lane & 15, hi = lane >> 4;
  const int raw = blockIdx.x;                  // 0..1023
  const int xcd = raw & 7;
  const int jj  = raw >> 3;                    // 0..127
  const int qt = 31 - (jj >> 2);               // 31..0
  const int bh = xcd * 4 + (jj & 3);           // 0..31
  const int b = bh >> 4, h = bh & 15;
  const int qb = qt << 6;

  const int qrow = b * T_ + qb + wv * 16 + lo;
  const u16* qp = q + (size_t)qrow * DIM_ + h * HD_;
  const bf16x8 qf0 = *(const bf16x8*)(qp + hi * 8);
  const bf16x8 qf1 = *(const bf16x8*)(qp + 32 + hi * 8);

  f32x4 o[4];
#pragma unroll
  for (int i = 0; i < 4; ++i) o[i] = (f32x4){0.f, 0.f, 0.f, 0.f};
  float lrun = 0.f;

  const int sl = tid & 63, skh = (tid >> 6) & 1, st0 = tid >> 7;
  const int srow = sl & 15, skk = skh * 32 + ((sl >> 4) << 3);
  const u16* kg0 = k + ((size_t)(b * T_ + st0 * 16 + srow)) * DIM_ + h * HD_ + skk;
  const u16* kg1 = kg0 + (size_t)32 * DIM_;
  const u16* vg0 = vt + ((size_t)(bh * HD_ + st0 * 16 + srow)) * T_ + skk;
  const u16* vg1 = vg0 + (size_t)32 * T_;
  const int wub = (tid >> 6) << 10;

  {
    gload_lds16(kg0, smem + wub);
    gload_lds16(kg1, smem + 4096 + wub);
    gload_lds16(vg0, smem + 8192 + wub);
    gload_lds16(vg1, smem + 12288 + wub);
    const int t1 = (qt >= 1) ? 1 : 0;
    const size_t ko = (size_t)t1 * 64 * DIM_;
    const size_t vo = (size_t)t1 * 64;
    unsigned char* b1 = smem + 16384;
    gload_lds16(kg0 + ko, b1 + wub);
    gload_lds16(kg1 + ko, b1 + 4096 + wub);
    gload_lds16(vg0 + vo, b1 + 8192 + wub);
    gload_lds16(vg1 + vo, b1 + 12288 + wub);
  }

  int sr = 0, sw = 2;
  for (int tix = 0; tix <= qt; ++tix) {
    __builtin_amdgcn_sched_barrier(0);
    if (tix < qt) {
      asm volatile("s_waitcnt vmcnt(4)" ::: "memory");
    } else {
      asm volatile("s_waitcnt vmcnt(0)" ::: "memory");
    }
    __builtin_amdgcn_s_barrier();
    __builtin_amdgcn_sched_barrier(0);
    if (tix + 2 <= qt) {
      const size_t ko = (size_t)(tix + 2) * 64 * DIM_;
      const size_t vo = (size_t)(tix + 2) * 64;
      unsigned char* base = smem + sw * 16384;
      gload_lds16(kg0 + ko, base + wub);
      gload_lds16(kg1 + ko, base + 4096 + wub);
      gload_lds16(vg0 + vo, base + 8192 + wub);
      gload_lds16(vg1 + vo, base + 12288 + wub);
    }
    const unsigned char* kb = smem + sr * 16384;
    const unsigned char* vb = kb + 8192;

    f32x4 stl[4];
#pragma unroll
    for (int kt = 0; kt < 4; ++kt) stl[kt] = (f32x4){0.f, 0.f, 0.f, 0.f};
    __builtin_amdgcn_s_setprio(1);
#pragma unroll
    for (int kh = 0; kh < 2; ++kh) {
      const bf16x8 qb_ = kh ? qf1 : qf0;
#pragma unroll
      for (int kt = 0; kt < 4; ++kt) {
        const bf16x8 af = *(const bf16x8*)(kb + (((kt * 2 + kh) * 64 + lane) << 4));
        stl[kt] = MFMA16(af, qb_, stl[kt]);
      }
    }
    __builtin_amdgcn_s_setprio(0);
    const bool diag = (tix == qt);
    // no-max softmax via 2^x: P = exp2(S * 0.1 * log2e) == e^(0.1 S).
    float ps = 0.f;
#pragma unroll
    for (int kt = 0; kt < 4; ++kt)
#pragma unroll
      for (int r = 0; r < 4; ++r) {
        float s = stl[kt][r] * SCALE2_;
        if (diag && (kt * 16 + hi * 4 + r > wv * 16 + lo)) s = -3e38f;
        const float e = fexp2(s);
        stl[kt][r] = e;
        ps += e;
      }
    ps += __shfl_xor(ps, 16, 64);
    ps += __shfl_xor(ps, 32, 64);
    lrun += ps;

    u32 pkv[4][2];
#pragma unroll
    for (int kt = 0; kt < 4; ++kt) {
      pkv[kt][0] = pk2(stl[kt][0], stl[kt][1]);
      pkv[kt][1] = pk2(stl[kt][2], stl[kt][3]);
    }
#pragma unroll
    for (int kh = 0; kh < 2; ++kh) {
      uint4 w4;
      u32* w4p = (u32*)&w4;
#pragma unroll
      for (int wd = 0; wd < 4; ++wd) {
        const int src = (2 * (hi & 1) + (wd >> 1)) * 16 + lo;
        const u32 a  = (u32)__shfl((int)pkv[2 * kh][wd & 1], src, 64);
        const u32 bb = (u32)__shfl((int)pkv[2 * kh + 1][wd & 1], src, 64);
        w4p[wd] = (hi < 2) ? a : bb;
      }
      const bf16x8 pf = __builtin_bit_cast(bf16x8, w4);
      __builtin_amdgcn_s_setprio(1);
#pragma unroll
      for (int dt = 0; dt < 4; ++dt) {
        const bf16x8 vf = *(const bf16x8*)(vb + (((dt * 2 + kh) * 64 + lane) << 4));
        o[dt] = MFMA16(vf, pf, o[dt]);
      }
      __builtin_amdgcn_s_setprio(0);
    }
    sr = (sr == 2) ? 0 : sr + 1;
    sw = (sw == 2) ? 0 : sw + 1;
  }

  const float inv = gate[(size_t)qrow * H_ + h] / lrun;
  u16* ybase = yt + (size_t)(qrow >> 4) * 16384 + (size_t)(h * 2) * 512
             + lo * 8 + (hi & 1) * 4;
#pragma unroll
  for (int dt = 0; dt < 4; ++dt) {
    ushort4 pq;
    pq.x = f2b(o[dt][0] * inv); pq.y = f2b(o[dt][1] * inv);
    pq.z = f2b(o[dt][2] * inv); pq.w = f2b(o[dt][3] * inv);
    const int c = (dt * 2 + (hi >> 1)) & 3;
    *(ushort4*)(ybase + (dt >> 1) * 512 + c * 128) = pq;
  }
}

// ---------------------------------------------------------------------------
extern "C" void kernel_launch(void* const* d_in, const int* in_sizes, int n_in,
                              void* d_out, int out_size, void* d_ws, size_t ws_size,
                              hipStream_t stream) {
  const float* x    = (const float*)d_in[0];
  const float* v1   = (const float*)d_in[1];
  const float* Wq   = (const float*)d_in[2];
  const float* Wk   = (const float*)d_in[3];
  const float* Wv   = (const float*)d_in[4];
  const float* Wp   = (const float*)d_in[5];
  const float* Wg   = (const float*)d_in[6];
  const float* lamb = (const float*)d_in[7];

  const size_t NX = (size_t)NROW * DIM_;        // 4M
  const size_t NW = (size_t)DIM_ * DIM_;        // 1M

  u16* q  = (u16*)d_ws;
  u16* k  = q + NX;
  u16* vt = k + NX;                             // [bh][d][t]
  u16* xb = vt + NX;                            // row-major x; later tiled y
  u16* wb = xb + NX;                            // wq|wk|wv row-major, wp tiled
  float* gate = (float*)(wb + 4 * NW);          // total ws: 40.25 MB

  const dim3 bb(256);

  convert_all<<<dim3(7936), bb, 0, stream>>>(x, Wq, Wk, Wv, Wp, Wg, xb, wb, gate);
  gemm_qkv<<<dim3(32, 24), bb, 0, stream>>>(xb, wb, q, k, vt, v1, lamb);
  attn3<<<dim3(1024), bb, 0, stream>>>(q, k, vt, gate, xb);
  gemm_proj<<<dim3(256), bb, 0, stream>>>(xb, wb + 3 * NW, (float*)d_out);
}